// Round 4
// baseline (257.290 us; speedup 1.0000x reference)
//
#include <hip/hip_runtime.h>
#include <math.h>

#define SENT 0x007FFFFFu         // fmap(-inf)

typedef __attribute__((ext_vector_type(8))) short bf16x8;
typedef __attribute__((ext_vector_type(4))) float f32x4;

__device__ __forceinline__ unsigned int fmap(float f) {
    unsigned int u = __float_as_uint(f);
    return (u & 0x80000000u) ? ~u : (u | 0x80000000u);
}
__device__ __forceinline__ float funmap(unsigned int u) {
    unsigned int bits = (u & 0x80000000u) ? (u ^ 0x80000000u) : ~u;
    return __uint_as_float(bits);
}
__device__ __forceinline__ short tobf(float f) {
    unsigned int u = __float_as_uint(f);
    u += 0x7FFFu + ((u >> 16) & 1u);
    return (short)(u >> 16);
}

// ---------------- sort-based path ----------------

// one thread per edge
__global__ void hist_kernel(const int* __restrict__ ei, unsigned int* __restrict__ counts, int E) {
    int i = blockIdx.x * blockDim.x + threadIdx.x;
    if (i < E) atomicAdd(&counts[ei[E + i]], 1u);
}

// block-level exclusive scan (1024/block) + block sums
__global__ void __launch_bounds__(1024) scan1_kernel(const unsigned int* __restrict__ counts,
                                                     unsigned int* __restrict__ offs,
                                                     unsigned int* __restrict__ bsum, int N) {
    __shared__ unsigned int s[1024];
    int tid = threadIdx.x;
    int i = blockIdx.x * 1024 + tid;
    unsigned int v = (i < N) ? counts[i] : 0u;
    s[tid] = v;
    __syncthreads();
    for (int d = 1; d < 1024; d <<= 1) {
        unsigned int t = (tid >= d) ? s[tid - d] : 0u;
        __syncthreads();
        s[tid] += t;
        __syncthreads();
    }
    if (i < N) offs[i] = s[tid] - v;
    if (tid == 1023) bsum[blockIdx.x] = s[1023];
}

__global__ void __launch_bounds__(1024) scan2_kernel(unsigned int* __restrict__ bsum, int nb) {
    __shared__ unsigned int s[1024];
    int tid = threadIdx.x;
    unsigned int v = (tid < nb) ? bsum[tid] : 0u;
    s[tid] = v;
    __syncthreads();
    for (int d = 1; d < 1024; d <<= 1) {
        unsigned int t = (tid >= d) ? s[tid - d] : 0u;
        __syncthreads();
        s[tid] += t;
        __syncthreads();
    }
    if (tid < nb) bsum[tid] = s[tid] - v;
}

__global__ void scan3_kernel(unsigned int* __restrict__ offs, unsigned int* __restrict__ cursor,
                             const unsigned int* __restrict__ bsum, int N, int E) {
    int i = blockIdx.x * blockDim.x + threadIdx.x;
    int stride = gridDim.x * blockDim.x;
    for (; i < N; i += stride) {
        unsigned int o = offs[i] + bsum[i >> 10];
        offs[i] = o;
        cursor[i] = o;
        if (i == 0) offs[N] = (unsigned int)E;
    }
}

// one thread per edge; NT store (write-once data)
__global__ void place_kernel(const int* __restrict__ ei, unsigned int* __restrict__ cursor,
                             int* __restrict__ ssrc, int E) {
    int i = blockIdx.x * blockDim.x + threadIdx.x;
    if (i >= E) return;
    int dst = ei[E + i];
    int src = ei[i];
    unsigned int pos = atomicAdd(&cursor[dst], 1u);
    __builtin_nontemporal_store(src, &ssrc[pos]);
}

// Fused segment-max + concat-GEMM-ReLU.
// 1 wave = 16 nodes. Per node: wave-parallel max over incoming x[src] rows (lane=channel),
// subtract x[node], stage row in wave-private LDS; then transpose to MFMA A-frags.
__global__ void __launch_bounds__(256) fused_kernel(const float* __restrict__ x,
                                                    const unsigned int* __restrict__ offs,
                                                    const int* __restrict__ ssrc,
                                                    const float* __restrict__ W,
                                                    const float* __restrict__ b,
                                                    float* __restrict__ out, int N) {
    __shared__ float T[4][16][68];   // [wave][row][ch] pad 68 -> 2-way max on b128 reads
    int lane = threadIdx.x & 63;
    int wid  = threadIdx.x >> 6;
    int r = lane & 15;
    int g = lane >> 4;
    float (*Tw)[68] = T[wid];

    // W fragments (row-major [128][64]) + bias
    bf16x8 Bf[4][4];
    #pragma unroll
    for (int nt = 0; nt < 4; ++nt)
        #pragma unroll
        for (int kt = 0; kt < 4; ++kt) {
            const float* wp = W + (size_t)(kt * 32 + g * 8) * 64 + nt * 16 + r;
            bf16x8 f;
            #pragma unroll
            for (int j = 0; j < 8; ++j) f[j] = tobf(wp[(size_t)j * 64]);
            Bf[nt][kt] = f;
        }
    float bias[4];
    #pragma unroll
    for (int nt = 0; nt < 4; ++nt) bias[nt] = b[nt * 16 + r];

    int nTiles = (N + 15) >> 4;
    int totalWaves = gridDim.x * 4;
    for (int tile = blockIdx.x * 4 + wid; tile < nTiles; tile += totalWaves) {
        int nodeBase = tile << 4;

        // ---- reduce phase: 16 nodes, lane = channel ----
        for (int q = 0; q < 16; ++q) {
            int n = nodeBase + q;
            float val = 0.0f;
            if (n < N) {
                int bs = (int)offs[n], en = (int)offs[n + 1];
                if (en > bs) {
                    float m0 = -INFINITY, m1 = -INFINITY, m2 = -INFINITY, m3 = -INFINITY;
                    for (int j0 = bs; j0 < en; j0 += 64) {
                        int cnt = min(64, en - j0);
                        int my = (j0 + lane < en) ? ssrc[j0 + lane] : 0;
                        int j = 0;
                        for (; j + 4 <= cnt; j += 4) {
                            int s0 = __shfl(my, j),     s1 = __shfl(my, j + 1);
                            int s2 = __shfl(my, j + 2), s3 = __shfl(my, j + 3);
                            m0 = fmaxf(m0, x[(size_t)s0 * 64 + lane]);
                            m1 = fmaxf(m1, x[(size_t)s1 * 64 + lane]);
                            m2 = fmaxf(m2, x[(size_t)s2 * 64 + lane]);
                            m3 = fmaxf(m3, x[(size_t)s3 * 64 + lane]);
                        }
                        for (; j < cnt; ++j) {
                            int s0 = __shfl(my, j);
                            m0 = fmaxf(m0, x[(size_t)s0 * 64 + lane]);
                        }
                    }
                    float m = fmaxf(fmaxf(m0, m1), fmaxf(m2, m3));
                    val = m - x[(size_t)n * 64 + lane];
                }
            }
            Tw[q][lane] = val;
        }
        // wave-private LDS handoff: drain ds_writes, pin ordering (guide rule #18)
        asm volatile("s_waitcnt lgkmcnt(0)" ::: "memory");
        __builtin_amdgcn_sched_barrier(0);

        // ---- MFMA phase ----
        int rowIdx = min(nodeBase + r, N - 1);
        const float* xp = x + (size_t)rowIdx * 64;

        bf16x8 Af[4];
        #pragma unroll
        for (int kt = 0; kt < 2; ++kt) {               // k in [0,64): x
            float4 lo = *(const float4*)(xp + kt * 32 + g * 8);
            float4 hi = *(const float4*)(xp + kt * 32 + g * 8 + 4);
            bf16x8 f;
            f[0] = tobf(lo.x); f[1] = tobf(lo.y); f[2] = tobf(lo.z); f[3] = tobf(lo.w);
            f[4] = tobf(hi.x); f[5] = tobf(hi.y); f[6] = tobf(hi.z); f[7] = tobf(hi.w);
            Af[kt] = f;
        }
        #pragma unroll
        for (int kt = 0; kt < 2; ++kt) {               // k in [64,128): xj from LDS
            const float* tp = &Tw[r][kt * 32 + g * 8];
            float4 lo = *(const float4*)tp;
            float4 hi = *(const float4*)(tp + 4);
            bf16x8 f;
            f[0] = tobf(lo.x); f[1] = tobf(lo.y); f[2] = tobf(lo.z); f[3] = tobf(lo.w);
            f[4] = tobf(hi.x); f[5] = tobf(hi.y); f[6] = tobf(hi.z); f[7] = tobf(hi.w);
            Af[2 + kt] = f;
        }
        asm volatile("s_waitcnt lgkmcnt(0)" ::: "memory");
        __builtin_amdgcn_sched_barrier(0);

        f32x4 acc[4];
        #pragma unroll
        for (int nt = 0; nt < 4; ++nt) {
            f32x4 a = {bias[nt], bias[nt], bias[nt], bias[nt]};
            acc[nt] = a;
        }
        #pragma unroll
        for (int nt = 0; nt < 4; ++nt)
            #pragma unroll
            for (int kt = 0; kt < 4; ++kt)
                acc[nt] = __builtin_amdgcn_mfma_f32_16x16x32_bf16(Af[kt], Bf[nt][kt], acc[nt], 0, 0, 0);

        #pragma unroll
        for (int nt = 0; nt < 4; ++nt)
            #pragma unroll
            for (int reg = 0; reg < 4; ++reg) {
                int nrow = nodeBase + g * 4 + reg;
                if (nrow < N)
                    out[(size_t)nrow * 64 + nt * 16 + r] = fmaxf(acc[nt][reg], 0.0f);
            }
    }
}

// ---------------- atomic fallback path ----------------

__global__ void init_kernel(uint4* __restrict__ ws, int n4) {
    int i = blockIdx.x * blockDim.x + threadIdx.x;
    int stride = gridDim.x * blockDim.x;
    uint4 v = make_uint4(SENT, SENT, SENT, SENT);
    for (; i < n4; i += stride) ws[i] = v;
}

__global__ void scatter_kernel(const float* __restrict__ x,
                               const int* __restrict__ ei,
                               unsigned int* __restrict__ ws, int E) {
    long long gid = (long long)blockIdx.x * blockDim.x + threadIdx.x;
    int e = (int)(gid >> 6);
    int lane = (int)(gid & 63);
    if (e >= E) return;
    int src = ei[e];
    int dst = ei[E + e];
    unsigned int m = fmap(x[(size_t)src * 64 + lane]);
    unsigned int* p = ws + (size_t)dst * 64 + lane;
    if (m > *p) atomicMax(p, m);
}

// fallback MLP: xj holds fmap-encoded max(x[src]); computes empty?0:(max - x[n])
__global__ void __launch_bounds__(256) mlp_kernel(const float* __restrict__ x,
                                                  const unsigned int* xj,
                                                  const float* __restrict__ W,
                                                  const float* __restrict__ b,
                                                  float* out, int N) {
    int lane = threadIdx.x & 63;
    int wid  = threadIdx.x >> 6;
    int r = lane & 15;
    int g = lane >> 4;

    bf16x8 Bf[4][4];
    #pragma unroll
    for (int nt = 0; nt < 4; ++nt)
        #pragma unroll
        for (int kt = 0; kt < 4; ++kt) {
            const float* wp = W + (size_t)(kt * 32 + g * 8) * 64 + nt * 16 + r;
            bf16x8 f;
            #pragma unroll
            for (int j = 0; j < 8; ++j) f[j] = tobf(wp[(size_t)j * 64]);
            Bf[nt][kt] = f;
        }
    float bias[4];
    #pragma unroll
    for (int nt = 0; nt < 4; ++nt) bias[nt] = b[nt * 16 + r];

    int nTiles = (N + 15) >> 4;
    int totalWaves = gridDim.x * 4;
    for (int tile = blockIdx.x * 4 + wid; tile < nTiles; tile += totalWaves) {
        int nodeBase = tile << 4;
        int rowIdx = min(nodeBase + r, N - 1);
        const float* xp = x + (size_t)rowIdx * 64;
        const unsigned int* jp = xj + (size_t)rowIdx * 64;

        bf16x8 Af[4];
        float xs[2][8];
        #pragma unroll
        for (int kt = 0; kt < 2; ++kt) {
            float4 lo = *(const float4*)(xp + kt * 32 + g * 8);
            float4 hi = *(const float4*)(xp + kt * 32 + g * 8 + 4);
            xs[kt][0] = lo.x; xs[kt][1] = lo.y; xs[kt][2] = lo.z; xs[kt][3] = lo.w;
            xs[kt][4] = hi.x; xs[kt][5] = hi.y; xs[kt][6] = hi.z; xs[kt][7] = hi.w;
            bf16x8 f;
            #pragma unroll
            for (int j = 0; j < 8; ++j) f[j] = tobf(xs[kt][j]);
            Af[kt] = f;
        }
        #pragma unroll
        for (int kt = 0; kt < 2; ++kt) {
            uint4 lo = *(const uint4*)(jp + kt * 32 + g * 8);
            uint4 hi = *(const uint4*)(jp + kt * 32 + g * 8 + 4);
            unsigned int uu[8] = {lo.x, lo.y, lo.z, lo.w, hi.x, hi.y, hi.z, hi.w};
            bf16x8 f;
            #pragma unroll
            for (int j = 0; j < 8; ++j) {
                bool empty = (uu[j] == SENT);
                float v = funmap(uu[j]);
                f[j] = tobf(empty ? 0.0f : (v - xs[kt][j]));
            }
            Af[2 + kt] = f;
        }

        f32x4 acc[4];
        #pragma unroll
        for (int nt = 0; nt < 4; ++nt) {
            f32x4 a = {bias[nt], bias[nt], bias[nt], bias[nt]};
            acc[nt] = a;
        }
        #pragma unroll
        for (int nt = 0; nt < 4; ++nt)
            #pragma unroll
            for (int kt = 0; kt < 4; ++kt)
                acc[nt] = __builtin_amdgcn_mfma_f32_16x16x32_bf16(Af[kt], Bf[nt][kt], acc[nt], 0, 0, 0);

        #pragma unroll
        for (int nt = 0; nt < 4; ++nt)
            #pragma unroll
            for (int reg = 0; reg < 4; ++reg) {
                int nrow = nodeBase + g * 4 + reg;
                if (nrow < N)
                    out[(size_t)nrow * 64 + nt * 16 + r] = fmaxf(acc[nt][reg], 0.0f);
            }
    }
}

extern "C" void kernel_launch(void* const* d_in, const int* in_sizes, int n_in,
                              void* d_out, int out_size, void* d_ws, size_t ws_size,
                              hipStream_t stream) {
    const float* x  = (const float*)d_in[0];
    const int*   ei = (const int*)d_in[1];
    const float* W  = (const float*)d_in[2];
    const float* b  = (const float*)d_in[3];
    float* out = (float*)d_out;

    int N = in_sizes[0] / 64;
    int E = in_sizes[1] / 2;
    int nb = (N + 1023) / 1024;

    size_t counts_b = (size_t)N * 4;
    size_t offs_b   = (size_t)(N + 1) * 4;
    size_t bsum_b   = (size_t)((nb + 63) & ~63) * 4;
    size_t ssrc_b   = (size_t)E * 4;
    size_t small    = counts_b + offs_b + counts_b + bsum_b + ssrc_b;

    bool sortPath = (ws_size >= small) && (nb <= 1024);
    if (sortPath) {
        char* base = (char*)d_ws;
        unsigned int* counts = (unsigned int*)base; base += counts_b;
        unsigned int* offs   = (unsigned int*)base; base += offs_b;
        unsigned int* cursor = (unsigned int*)base; base += counts_b;
        unsigned int* bsum   = (unsigned int*)base; base += bsum_b;
        int*          ssrc   = (int*)base;

        int eg = (E + 255) / 256;
        hipMemsetAsync(counts, 0, counts_b, stream);
        hist_kernel<<<eg, 256, 0, stream>>>(ei, counts, E);
        scan1_kernel<<<nb, 1024, 0, stream>>>(counts, offs, bsum, N);
        scan2_kernel<<<1, 1024, 0, stream>>>(bsum, nb);
        scan3_kernel<<<256, 256, 0, stream>>>(offs, cursor, bsum, N, E);
        place_kernel<<<eg, 256, 0, stream>>>(ei, cursor, ssrc, E);
        int nTiles = (N + 15) >> 4;
        fused_kernel<<<(nTiles + 3) / 4, 256, 0, stream>>>(x, offs, ssrc, W, b, out, N);
    } else {
        size_t need = (size_t)N * 64 * 4;
        unsigned int* scratch = (ws_size >= need) ? (unsigned int*)d_ws : (unsigned int*)d_out;
        init_kernel<<<2048, 256, 0, stream>>>((uint4*)scratch, N * 16);
        long long sthreads = (long long)E * 64;
        int sblocks = (int)((sthreads + 255) / 256);
        scatter_kernel<<<sblocks, 256, 0, stream>>>(x, ei, scratch, E);
        mlp_kernel<<<782, 256, 0, stream>>>(x, scratch, W, b, out, N);
    }
}

// Round 5
// 181.883 us; speedup vs baseline: 1.4146x; 1.4146x over previous
//
#include <hip/hip_runtime.h>
#include <math.h>

#define SENT 0x007FFFFFu         // fmap(-inf)
#define NA 64                    // number of hist/place blocks (chunks)
#define SB_SHIFT 10              // 1024 nodes per super-bucket
#define SB_MASK ((1u << SB_SHIFT) - 1u)
#define NB 256                   // nodes per fusedB block

typedef __attribute__((ext_vector_type(8))) short bf16x8;
typedef __attribute__((ext_vector_type(4))) float f32x4;

__device__ __forceinline__ unsigned int fmap(float f) {
    unsigned int u = __float_as_uint(f);
    return (u & 0x80000000u) ? ~u : (u | 0x80000000u);
}
__device__ __forceinline__ float funmap(unsigned int u) {
    unsigned int bits = (u & 0x80000000u) ? (u ^ 0x80000000u) : ~u;
    return __uint_as_float(bits);
}
__device__ __forceinline__ short tobf(float f) {
    unsigned int u = __float_as_uint(f);
    u += 0x7FFFu + ((u >> 16) & 1u);
    return (short)(u >> 16);
}

// ---------- coarse counting sort (no global atomics) ----------

// per-(sb, block) histogram
__global__ void __launch_bounds__(256) histA_kernel(const int* __restrict__ ei,
                                                    unsigned* __restrict__ counts2,
                                                    int E, int nsb, int chunk) {
    __shared__ unsigned h[1024];
    for (int t = threadIdx.x; t < nsb; t += 256) h[t] = 0u;
    __syncthreads();
    int beg = blockIdx.x * chunk;
    int end = min(beg + chunk, E);
    for (int i = beg + threadIdx.x; i < end; i += 256)
        atomicAdd(&h[((unsigned)ei[E + i]) >> SB_SHIFT], 1u);
    __syncthreads();
    for (int t = threadIdx.x; t < nsb; t += 256)
        counts2[t * NA + blockIdx.x] = h[t];
}

// single-block exclusive scan over L = nsb*NA entries (sb-major)
__global__ void __launch_bounds__(1024) scanL_kernel(const unsigned* __restrict__ c2,
                                                     unsigned* __restrict__ base, int L) {
    __shared__ unsigned s[1024];
    __shared__ unsigned carry_s;
    if (threadIdx.x == 0) carry_s = 0u;
    __syncthreads();
    for (int chunk = 0; chunk < L; chunk += 1024) {
        int i = chunk + threadIdx.x;
        unsigned v = (i < L) ? c2[i] : 0u;
        s[threadIdx.x] = v;
        __syncthreads();
        for (int d = 1; d < 1024; d <<= 1) {
            unsigned t = (threadIdx.x >= d) ? s[threadIdx.x - d] : 0u;
            __syncthreads();
            s[threadIdx.x] += t;
            __syncthreads();
        }
        unsigned carry = carry_s;
        if (i < L) base[i] = carry + s[threadIdx.x] - v;
        __syncthreads();
        if (threadIdx.x == 1023) carry_s = carry + s[1023];
        __syncthreads();
    }
    if (threadIdx.x == 0) base[L] = carry_s;
}

// placement: block-local LDS cursors; stores stream into exclusive (sb,blk) regions
__global__ void __launch_bounds__(256) placeB_kernel(const int* __restrict__ ei,
                                                     const unsigned* __restrict__ base,
                                                     unsigned* __restrict__ ssrc,
                                                     int E, int nsb, int chunk) {
    __shared__ unsigned fill[1024];
    for (int t = threadIdx.x; t < nsb; t += 256) fill[t] = 0u;
    __syncthreads();
    int beg = blockIdx.x * chunk;
    int end = min(beg + chunk, E);
    for (int i = beg + threadIdx.x; i < end; i += 256) {
        unsigned src = (unsigned)ei[i];
        unsigned dst = (unsigned)ei[E + i];
        unsigned sb = dst >> SB_SHIFT;
        unsigned pos = base[sb * NA + blockIdx.x] + atomicAdd(&fill[sb], 1u);
        ssrc[pos] = (src << SB_SHIFT) | (dst & SB_MASK);
    }
}

// ---------- fused LDS segment-max + concat-GEMM-ReLU ----------
// Block = 256 nodes. LDS M[256][64] (u32, fmap-encoded, XOR-swizzled).
// 8 waves scan the super-bucket's packed edges, ballot-extract hits,
// 4-deep independent gathers + LDS atomicMax. Then MFMA epilogue.
__global__ void __launch_bounds__(512) fusedB_kernel(const float* __restrict__ x,
                                                     const unsigned* __restrict__ base,
                                                     const unsigned* __restrict__ ssrc,
                                                     const float* __restrict__ W,
                                                     const float* __restrict__ b,
                                                     float* __restrict__ out,
                                                     int N, int nsb) {
    __shared__ unsigned M[NB * 64];      // 64 KiB
    int tid = threadIdx.x;
    int lane = tid & 63;
    int wid = tid >> 6;                  // 8 waves

    for (int i = tid; i < NB * 64; i += 512) M[i] = SENT;

    int nodeBase = blockIdx.x * NB;
    unsigned sb = (unsigned)nodeBase >> SB_SHIFT;
    int lo = nodeBase & (int)SB_MASK;
    int beg = (int)base[sb * NA];
    int end = (int)base[(sb + 1) * NA];
    __syncthreads();

    // ---- reduce phase ----
    for (int idx0 = beg + wid * 64; idx0 < end; idx0 += 512) {
        int i = idx0 + lane;
        unsigned p = (i < end) ? ssrc[i] : 0u;
        int dl = (int)(p & SB_MASK) - lo;
        bool hit = (i < end) && ((unsigned)dl < (unsigned)NB);
        unsigned long long mask = __ballot(hit);
        while (mask) {
            unsigned long long m = mask;
            int b0 = __ffsll((unsigned long long)m) - 1; m &= m - 1;
            int b1 = m ? __ffsll((unsigned long long)m) - 1 : b0; m &= m - 1;
            int b2 = m ? __ffsll((unsigned long long)m) - 1 : b0; m &= m - 1;
            int b3 = m ? __ffsll((unsigned long long)m) - 1 : b0; m &= m - 1;
            mask = m;
            unsigned p0 = __shfl(p, b0), p1 = __shfl(p, b1);
            unsigned p2 = __shfl(p, b2), p3 = __shfl(p, b3);
            float v0 = x[(size_t)(p0 >> SB_SHIFT) * 64 + lane];
            float v1 = x[(size_t)(p1 >> SB_SHIFT) * 64 + lane];
            float v2 = x[(size_t)(p2 >> SB_SHIFT) * 64 + lane];
            float v3 = x[(size_t)(p3 >> SB_SHIFT) * 64 + lane];
            int r0 = (int)(p0 & SB_MASK) - lo;
            int r1 = (int)(p1 & SB_MASK) - lo;
            int r2 = (int)(p2 & SB_MASK) - lo;
            int r3 = (int)(p3 & SB_MASK) - lo;
            atomicMax(&M[r0 * 64 + (lane ^ ((r0 & 7) << 2))], fmap(v0));
            atomicMax(&M[r1 * 64 + (lane ^ ((r1 & 7) << 2))], fmap(v1));
            atomicMax(&M[r2 * 64 + (lane ^ ((r2 & 7) << 2))], fmap(v2));
            atomicMax(&M[r3 * 64 + (lane ^ ((r3 & 7) << 2))], fmap(v3));
        }
    }
    __syncthreads();

    // ---- MFMA phase ----
    int r = lane & 15;
    int g = lane >> 4;

    bf16x8 Bf[4][4];
    #pragma unroll
    for (int nt = 0; nt < 4; ++nt)
        #pragma unroll
        for (int kt = 0; kt < 4; ++kt) {
            const float* wp = W + (size_t)(kt * 32 + g * 8) * 64 + nt * 16 + r;
            bf16x8 f;
            #pragma unroll
            for (int j = 0; j < 8; ++j) f[j] = tobf(wp[(size_t)j * 64]);
            Bf[nt][kt] = f;
        }
    float bias[4];
    #pragma unroll
    for (int nt = 0; nt < 4; ++nt) bias[nt] = b[nt * 16 + r];

    for (int tile = wid; tile < NB / 16; tile += 8) {
        int tb = nodeBase + tile * 16;
        int rowIdx = min(tb + r, N - 1);
        const float* xp = x + (size_t)rowIdx * 64;
        int lrow = tile * 16 + r;
        int swz = (lrow & 7) << 2;

        bf16x8 Af[4];
        float xs[2][8];
        #pragma unroll
        for (int kt = 0; kt < 2; ++kt) {             // k in [0,64): x
            float4 flo = *(const float4*)(xp + kt * 32 + g * 8);
            float4 fhi = *(const float4*)(xp + kt * 32 + g * 8 + 4);
            xs[kt][0] = flo.x; xs[kt][1] = flo.y; xs[kt][2] = flo.z; xs[kt][3] = flo.w;
            xs[kt][4] = fhi.x; xs[kt][5] = fhi.y; xs[kt][6] = fhi.z; xs[kt][7] = fhi.w;
            bf16x8 f;
            #pragma unroll
            for (int j = 0; j < 8; ++j) f[j] = tobf(xs[kt][j]);
            Af[kt] = f;
        }
        #pragma unroll
        for (int kt = 0; kt < 2; ++kt) {             // k in [64,128): xj from LDS
            int ch0 = kt * 32 + g * 8;
            uint4 ulo = *(const uint4*)&M[lrow * 64 + (ch0 ^ swz)];
            uint4 uhi = *(const uint4*)&M[lrow * 64 + ((ch0 + 4) ^ swz)];
            unsigned uu[8] = {ulo.x, ulo.y, ulo.z, ulo.w, uhi.x, uhi.y, uhi.z, uhi.w};
            bf16x8 f;
            #pragma unroll
            for (int j = 0; j < 8; ++j) {
                bool empty = (uu[j] == SENT);
                float v = funmap(uu[j]);
                f[j] = tobf(empty ? 0.0f : (v - xs[kt][j]));
            }
            Af[2 + kt] = f;
        }

        f32x4 acc[4];
        #pragma unroll
        for (int nt = 0; nt < 4; ++nt) {
            f32x4 a = {bias[nt], bias[nt], bias[nt], bias[nt]};
            acc[nt] = a;
        }
        #pragma unroll
        for (int nt = 0; nt < 4; ++nt)
            #pragma unroll
            for (int kt = 0; kt < 4; ++kt)
                acc[nt] = __builtin_amdgcn_mfma_f32_16x16x32_bf16(Af[kt], Bf[nt][kt], acc[nt], 0, 0, 0);

        #pragma unroll
        for (int nt = 0; nt < 4; ++nt)
            #pragma unroll
            for (int reg = 0; reg < 4; ++reg) {
                int nrow = tb + g * 4 + reg;
                if (nrow < N)
                    out[(size_t)nrow * 64 + nt * 16 + r] = fmaxf(acc[nt][reg], 0.0f);
            }
    }
}

// ---------------- atomic fallback path ----------------

__global__ void init_kernel(uint4* __restrict__ ws, int n4) {
    int i = blockIdx.x * blockDim.x + threadIdx.x;
    int stride = gridDim.x * blockDim.x;
    uint4 v = make_uint4(SENT, SENT, SENT, SENT);
    for (; i < n4; i += stride) ws[i] = v;
}

__global__ void scatter_kernel(const float* __restrict__ x,
                               const int* __restrict__ ei,
                               unsigned int* __restrict__ ws, int E) {
    long long gid = (long long)blockIdx.x * blockDim.x + threadIdx.x;
    int e = (int)(gid >> 6);
    int lane = (int)(gid & 63);
    if (e >= E) return;
    int src = ei[e];
    int dst = ei[E + e];
    unsigned int m = fmap(x[(size_t)src * 64 + lane]);
    unsigned int* p = ws + (size_t)dst * 64 + lane;
    if (m > *p) atomicMax(p, m);
}

__global__ void __launch_bounds__(256) mlp_kernel(const float* __restrict__ x,
                                                  const unsigned int* xj,
                                                  const float* __restrict__ W,
                                                  const float* __restrict__ b,
                                                  float* out, int N) {
    int lane = threadIdx.x & 63;
    int wid  = threadIdx.x >> 6;
    int r = lane & 15;
    int g = lane >> 4;

    bf16x8 Bf[4][4];
    #pragma unroll
    for (int nt = 0; nt < 4; ++nt)
        #pragma unroll
        for (int kt = 0; kt < 4; ++kt) {
            const float* wp = W + (size_t)(kt * 32 + g * 8) * 64 + nt * 16 + r;
            bf16x8 f;
            #pragma unroll
            for (int j = 0; j < 8; ++j) f[j] = tobf(wp[(size_t)j * 64]);
            Bf[nt][kt] = f;
        }
    float bias[4];
    #pragma unroll
    for (int nt = 0; nt < 4; ++nt) bias[nt] = b[nt * 16 + r];

    int nTiles = (N + 15) >> 4;
    int totalWaves = gridDim.x * 4;
    for (int tile = blockIdx.x * 4 + wid; tile < nTiles; tile += totalWaves) {
        int nodeBase = tile << 4;
        int rowIdx = min(nodeBase + r, N - 1);
        const float* xp = x + (size_t)rowIdx * 64;
        const unsigned int* jp = xj + (size_t)rowIdx * 64;

        bf16x8 Af[4];
        float xs[2][8];
        #pragma unroll
        for (int kt = 0; kt < 2; ++kt) {
            float4 flo = *(const float4*)(xp + kt * 32 + g * 8);
            float4 fhi = *(const float4*)(xp + kt * 32 + g * 8 + 4);
            xs[kt][0] = flo.x; xs[kt][1] = flo.y; xs[kt][2] = flo.z; xs[kt][3] = flo.w;
            xs[kt][4] = fhi.x; xs[kt][5] = fhi.y; xs[kt][6] = fhi.z; xs[kt][7] = fhi.w;
            bf16x8 f;
            #pragma unroll
            for (int j = 0; j < 8; ++j) f[j] = tobf(xs[kt][j]);
            Af[kt] = f;
        }
        #pragma unroll
        for (int kt = 0; kt < 2; ++kt) {
            uint4 ulo = *(const uint4*)(jp + kt * 32 + g * 8);
            uint4 uhi = *(const uint4*)(jp + kt * 32 + g * 8 + 4);
            unsigned int uu[8] = {ulo.x, ulo.y, ulo.z, ulo.w, uhi.x, uhi.y, uhi.z, uhi.w};
            bf16x8 f;
            #pragma unroll
            for (int j = 0; j < 8; ++j) {
                bool empty = (uu[j] == SENT);
                float v = funmap(uu[j]);
                f[j] = tobf(empty ? 0.0f : (v - xs[kt][j]));
            }
            Af[2 + kt] = f;
        }

        f32x4 acc[4];
        #pragma unroll
        for (int nt = 0; nt < 4; ++nt) {
            f32x4 a = {bias[nt], bias[nt], bias[nt], bias[nt]};
            acc[nt] = a;
        }
        #pragma unroll
        for (int nt = 0; nt < 4; ++nt)
            #pragma unroll
            for (int kt = 0; kt < 4; ++kt)
                acc[nt] = __builtin_amdgcn_mfma_f32_16x16x32_bf16(Af[kt], Bf[nt][kt], acc[nt], 0, 0, 0);

        #pragma unroll
        for (int nt = 0; nt < 4; ++nt)
            #pragma unroll
            for (int reg = 0; reg < 4; ++reg) {
                int nrow = nodeBase + g * 4 + reg;
                if (nrow < N)
                    out[(size_t)nrow * 64 + nt * 16 + r] = fmaxf(acc[nt][reg], 0.0f);
            }
    }
}

extern "C" void kernel_launch(void* const* d_in, const int* in_sizes, int n_in,
                              void* d_out, int out_size, void* d_ws, size_t ws_size,
                              hipStream_t stream) {
    const float* x  = (const float*)d_in[0];
    const int*   ei = (const int*)d_in[1];
    const float* W  = (const float*)d_in[2];
    const float* b  = (const float*)d_in[3];
    float* out = (float*)d_out;

    int N = in_sizes[0] / 64;
    int E = in_sizes[1] / 2;

    int nsb = (N + (1 << SB_SHIFT) - 1) >> SB_SHIFT;
    int L = nsb * NA;
    int chunk = (E + NA - 1) / NA;

    size_t counts2_b = (size_t)L * 4;
    size_t base_b    = (size_t)(L + 1) * 4;
    size_t ssrc_b    = (size_t)E * 4;
    size_t need      = counts2_b + base_b + ssrc_b;

    bool sortPath = (ws_size >= need) && (N <= (1 << 20)) && (nsb <= 1024);
    if (sortPath) {
        char* p = (char*)d_ws;
        unsigned* counts2 = (unsigned*)p; p += counts2_b;
        unsigned* basep   = (unsigned*)p; p += base_b;
        unsigned* ssrc    = (unsigned*)p;

        histA_kernel<<<NA, 256, 0, stream>>>(ei, counts2, E, nsb, chunk);
        scanL_kernel<<<1, 1024, 0, stream>>>(counts2, basep, L);
        placeB_kernel<<<NA, 256, 0, stream>>>(ei, basep, ssrc, E, nsb, chunk);
        int gridB = (N + NB - 1) / NB;
        fusedB_kernel<<<gridB, 512, 0, stream>>>(x, basep, ssrc, W, b, out, N, nsb);
    } else {
        size_t need2 = (size_t)N * 64 * 4;
        unsigned int* scratch = (ws_size >= need2) ? (unsigned int*)d_ws : (unsigned int*)d_out;
        init_kernel<<<2048, 256, 0, stream>>>((uint4*)scratch, N * 16);
        long long sthreads = (long long)E * 64;
        int sblocks = (int)((sthreads + 255) / 256);
        scatter_kernel<<<sblocks, 256, 0, stream>>>(x, ei, scratch, E);
        mlp_kernel<<<782, 256, 0, stream>>>(x, scratch, W, b, out, N);
    }
}

// Round 6
// 158.337 us; speedup vs baseline: 1.6250x; 1.1487x over previous
//
#include <hip/hip_runtime.h>
#include <math.h>

#define SENT 0x007FFFFFu         // fmap(-inf)
#define NA 128                   // hist/place chunk blocks
#define SB_SHIFT 7               // 128 nodes per bucket == fusedB block
#define SB_MASK ((1u << SB_SHIFT) - 1u)
#define NB 128                   // nodes per fusedB block
#define PITCH 68                 // LDS row pitch (words): conflict-free both phases

typedef __attribute__((ext_vector_type(8))) short bf16x8;
typedef __attribute__((ext_vector_type(4))) float f32x4;

__device__ __forceinline__ unsigned int fmap(float f) {
    unsigned int u = __float_as_uint(f);
    return (u & 0x80000000u) ? ~u : (u | 0x80000000u);
}
__device__ __forceinline__ float funmap(unsigned int u) {
    unsigned int bits = (u & 0x80000000u) ? (u ^ 0x80000000u) : ~u;
    return __uint_as_float(bits);
}
__device__ __forceinline__ short tobf(float f) {
    unsigned int u = __float_as_uint(f);
    u += 0x7FFFu + ((u >> 16) & 1u);
    return (short)(u >> 16);
}

// ---------- counting sort by 128-node bucket (no global atomics) ----------

// per-(sb, chunk-block) histogram; writes full counts2 (no memset needed)
__global__ void __launch_bounds__(256) histA_kernel(const int* __restrict__ ei,
                                                    unsigned* __restrict__ counts2,
                                                    int E, int nsb, int chunk) {
    __shared__ unsigned h[1024];
    for (int t = threadIdx.x; t < nsb; t += 256) h[t] = 0u;
    __syncthreads();
    int beg = blockIdx.x * chunk;
    int end = min(beg + chunk, E);
    for (int i = beg + threadIdx.x; i < end; i += 256)
        atomicAdd(&h[((unsigned)ei[E + i]) >> SB_SHIFT], 1u);
    __syncthreads();
    for (int t = threadIdx.x; t < nsb; t += 256)
        counts2[(size_t)t * NA + blockIdx.x] = h[t];
}

// one wave per sb: in-place exclusive scan of counts2[sb][0..NA-1]; row total -> sbtot
__global__ void __launch_bounds__(512) rowscan_kernel(unsigned* __restrict__ counts2,
                                                      unsigned* __restrict__ sbtot, int nsb) {
    int lane = threadIdx.x & 63;
    int sb = blockIdx.x * 8 + (threadIdx.x >> 6);
    if (sb >= nsb) return;
    unsigned* row = counts2 + (size_t)sb * NA;
    unsigned a = row[lane];
    unsigned c = row[64 + lane];
    unsigned local = a + c;
    unsigned incl = local;
    #pragma unroll
    for (int d = 1; d < 64; d <<= 1) {
        unsigned t = __shfl_up(incl, d);
        if (lane >= d) incl += t;
    }
    unsigned excl = incl - local;
    row[lane] = excl;
    row[64 + lane] = excl + a;
    if (lane == 63) sbtot[sb] = incl;
}

// single-block exclusive scan of sbtot (nsb <= 1024) -> sbbase[0..nsb]
__global__ void __launch_bounds__(1024) sbscan_kernel(const unsigned* __restrict__ sbtot,
                                                      unsigned* __restrict__ sbbase, int nsb) {
    __shared__ unsigned s[1024];
    int tid = threadIdx.x;
    unsigned v = (tid < nsb) ? sbtot[tid] : 0u;
    s[tid] = v;
    __syncthreads();
    for (int d = 1; d < 1024; d <<= 1) {
        unsigned t = (tid >= d) ? s[tid - d] : 0u;
        __syncthreads();
        s[tid] += t;
        __syncthreads();
    }
    if (tid < nsb) {
        sbbase[tid] = s[tid] - v;
        if (tid == nsb - 1) sbbase[nsb] = s[tid];
    }
}

// placement: LDS cursors preloaded with sbbase+rowbase; exclusive (sb,blk) regions
__global__ void __launch_bounds__(256) placeB_kernel(const int* __restrict__ ei,
                                                     const unsigned* __restrict__ counts2,
                                                     const unsigned* __restrict__ sbbase,
                                                     unsigned* __restrict__ ssrc,
                                                     int E, int nsb, int chunk) {
    __shared__ unsigned fill[1024];
    for (int t = threadIdx.x; t < nsb; t += 256)
        fill[t] = sbbase[t] + counts2[(size_t)t * NA + blockIdx.x];
    __syncthreads();
    int beg = blockIdx.x * chunk;
    int end = min(beg + chunk, E);
    for (int i = beg + threadIdx.x; i < end; i += 256) {
        unsigned src = (unsigned)ei[i];
        unsigned dst = (unsigned)ei[E + i];
        unsigned pos = atomicAdd(&fill[dst >> SB_SHIFT], 1u);
        ssrc[pos] = (src << SB_SHIFT) | (dst & SB_MASK);
    }
}

// ---------- fused LDS segment-max + concat-GEMM-ReLU (bucket == block) ----------
__global__ void __launch_bounds__(512) fusedB_kernel(const float* __restrict__ x,
                                                     const unsigned* __restrict__ sbbase,
                                                     const unsigned* __restrict__ ssrc,
                                                     const float* __restrict__ W,
                                                     const float* __restrict__ b,
                                                     float* __restrict__ out, int N) {
    __shared__ unsigned M[NB * PITCH];   // 34.8 KiB
    int tid = threadIdx.x;
    int lane = tid & 63;
    int wid = tid >> 6;                  // 8 waves

    for (int i = tid; i < NB * PITCH; i += 512) M[i] = SENT;

    int nodeBase = blockIdx.x * NB;
    int beg = (int)sbbase[blockIdx.x];
    int end = (int)sbbase[blockIdx.x + 1];
    __syncthreads();

    // ---- reduce: every edge in [beg,end) targets this block's 128 nodes ----
    for (int i0 = beg + wid * 64; i0 < end; i0 += 512) {
        int i = i0 + lane;
        unsigned p = (i < end) ? ssrc[i] : 0u;
        int cnt = min(64, end - i0);
        for (int j = 0; j < cnt; j += 4) {
            // tail: duplicate edge j (atomicMax idempotent)
            unsigned p0 = __shfl(p, j);
            unsigned p1 = (j + 1 < cnt) ? __shfl(p, j + 1) : p0;
            unsigned p2 = (j + 2 < cnt) ? __shfl(p, j + 2) : p0;
            unsigned p3 = (j + 3 < cnt) ? __shfl(p, j + 3) : p0;
            float v0 = x[(size_t)(p0 >> SB_SHIFT) * 64 + lane];
            float v1 = x[(size_t)(p1 >> SB_SHIFT) * 64 + lane];
            float v2 = x[(size_t)(p2 >> SB_SHIFT) * 64 + lane];
            float v3 = x[(size_t)(p3 >> SB_SHIFT) * 64 + lane];
            atomicMax(&M[(p0 & SB_MASK) * PITCH + lane], fmap(v0));
            atomicMax(&M[(p1 & SB_MASK) * PITCH + lane], fmap(v1));
            atomicMax(&M[(p2 & SB_MASK) * PITCH + lane], fmap(v2));
            atomicMax(&M[(p3 & SB_MASK) * PITCH + lane], fmap(v3));
        }
    }
    __syncthreads();

    // ---- MFMA concat-GEMM-ReLU: 8 tiles of 16 rows, 1 per wave ----
    int r = lane & 15;
    int g = lane >> 4;

    bf16x8 Bf[4][4];
    #pragma unroll
    for (int nt = 0; nt < 4; ++nt)
        #pragma unroll
        for (int kt = 0; kt < 4; ++kt) {
            const float* wp = W + (size_t)(kt * 32 + g * 8) * 64 + nt * 16 + r;
            bf16x8 f;
            #pragma unroll
            for (int j = 0; j < 8; ++j) f[j] = tobf(wp[(size_t)j * 64]);
            Bf[nt][kt] = f;
        }
    float bias[4];
    #pragma unroll
    for (int nt = 0; nt < 4; ++nt) bias[nt] = b[nt * 16 + r];

    {
        int tb = nodeBase + wid * 16;
        int rowIdx = min(tb + r, N - 1);
        const float* xp = x + (size_t)rowIdx * 64;
        int lrow = wid * 16 + r;

        bf16x8 Af[4];
        float xs[2][8];
        #pragma unroll
        for (int kt = 0; kt < 2; ++kt) {             // k in [0,64): x
            float4 flo = *(const float4*)(xp + kt * 32 + g * 8);
            float4 fhi = *(const float4*)(xp + kt * 32 + g * 8 + 4);
            xs[kt][0] = flo.x; xs[kt][1] = flo.y; xs[kt][2] = flo.z; xs[kt][3] = flo.w;
            xs[kt][4] = fhi.x; xs[kt][5] = fhi.y; xs[kt][6] = fhi.z; xs[kt][7] = fhi.w;
            bf16x8 f;
            #pragma unroll
            for (int j = 0; j < 8; ++j) f[j] = tobf(xs[kt][j]);
            Af[kt] = f;
        }
        #pragma unroll
        for (int kt = 0; kt < 2; ++kt) {             // k in [64,128): xj from LDS
            int ch0 = kt * 32 + g * 8;
            uint4 ulo = *(const uint4*)&M[lrow * PITCH + ch0];
            uint4 uhi = *(const uint4*)&M[lrow * PITCH + ch0 + 4];
            unsigned uu[8] = {ulo.x, ulo.y, ulo.z, ulo.w, uhi.x, uhi.y, uhi.z, uhi.w};
            bf16x8 f;
            #pragma unroll
            for (int j = 0; j < 8; ++j) {
                bool empty = (uu[j] == SENT);
                float v = funmap(uu[j]);
                f[j] = tobf(empty ? 0.0f : (v - xs[kt][j]));
            }
            Af[2 + kt] = f;
        }

        f32x4 acc[4];
        #pragma unroll
        for (int nt = 0; nt < 4; ++nt) {
            f32x4 a = {bias[nt], bias[nt], bias[nt], bias[nt]};
            acc[nt] = a;
        }
        #pragma unroll
        for (int nt = 0; nt < 4; ++nt)
            #pragma unroll
            for (int kt = 0; kt < 4; ++kt)
                acc[nt] = __builtin_amdgcn_mfma_f32_16x16x32_bf16(Af[kt], Bf[nt][kt], acc[nt], 0, 0, 0);

        #pragma unroll
        for (int nt = 0; nt < 4; ++nt)
            #pragma unroll
            for (int reg = 0; reg < 4; ++reg) {
                int nrow = tb + g * 4 + reg;
                if (nrow < N)
                    out[(size_t)nrow * 64 + nt * 16 + r] = fmaxf(acc[nt][reg], 0.0f);
            }
    }
}

// ---------------- atomic fallback path ----------------

__global__ void init_kernel(uint4* __restrict__ ws, int n4) {
    int i = blockIdx.x * blockDim.x + threadIdx.x;
    int stride = gridDim.x * blockDim.x;
    uint4 v = make_uint4(SENT, SENT, SENT, SENT);
    for (; i < n4; i += stride) ws[i] = v;
}

__global__ void scatter_kernel(const float* __restrict__ x,
                               const int* __restrict__ ei,
                               unsigned int* __restrict__ ws, int E) {
    long long gid = (long long)blockIdx.x * blockDim.x + threadIdx.x;
    int e = (int)(gid >> 6);
    int lane = (int)(gid & 63);
    if (e >= E) return;
    int src = ei[e];
    int dst = ei[E + e];
    unsigned int m = fmap(x[(size_t)src * 64 + lane]);
    unsigned int* p = ws + (size_t)dst * 64 + lane;
    if (m > *p) atomicMax(p, m);
}

__global__ void __launch_bounds__(256) mlp_kernel(const float* __restrict__ x,
                                                  const unsigned int* xj,
                                                  const float* __restrict__ W,
                                                  const float* __restrict__ b,
                                                  float* out, int N) {
    int lane = threadIdx.x & 63;
    int wid  = threadIdx.x >> 6;
    int r = lane & 15;
    int g = lane >> 4;

    bf16x8 Bf[4][4];
    #pragma unroll
    for (int nt = 0; nt < 4; ++nt)
        #pragma unroll
        for (int kt = 0; kt < 4; ++kt) {
            const float* wp = W + (size_t)(kt * 32 + g * 8) * 64 + nt * 16 + r;
            bf16x8 f;
            #pragma unroll
            for (int j = 0; j < 8; ++j) f[j] = tobf(wp[(size_t)j * 64]);
            Bf[nt][kt] = f;
        }
    float bias[4];
    #pragma unroll
    for (int nt = 0; nt < 4; ++nt) bias[nt] = b[nt * 16 + r];

    int nTiles = (N + 15) >> 4;
    int totalWaves = gridDim.x * 4;
    for (int tile = blockIdx.x * 4 + wid; tile < nTiles; tile += totalWaves) {
        int nodeBase = tile << 4;
        int rowIdx = min(nodeBase + r, N - 1);
        const float* xp = x + (size_t)rowIdx * 64;
        const unsigned int* jp = xj + (size_t)rowIdx * 64;

        bf16x8 Af[4];
        float xs[2][8];
        #pragma unroll
        for (int kt = 0; kt < 2; ++kt) {
            float4 flo = *(const float4*)(xp + kt * 32 + g * 8);
            float4 fhi = *(const float4*)(xp + kt * 32 + g * 8 + 4);
            xs[kt][0] = flo.x; xs[kt][1] = flo.y; xs[kt][2] = flo.z; xs[kt][3] = flo.w;
            xs[kt][4] = fhi.x; xs[kt][5] = fhi.y; xs[kt][6] = fhi.z; xs[kt][7] = fhi.w;
            bf16x8 f;
            #pragma unroll
            for (int j = 0; j < 8; ++j) f[j] = tobf(xs[kt][j]);
            Af[kt] = f;
        }
        #pragma unroll
        for (int kt = 0; kt < 2; ++kt) {
            uint4 ulo = *(const uint4*)(jp + kt * 32 + g * 8);
            uint4 uhi = *(const uint4*)(jp + kt * 32 + g * 8 + 4);
            unsigned int uu[8] = {ulo.x, ulo.y, ulo.z, ulo.w, uhi.x, uhi.y, uhi.z, uhi.w};
            bf16x8 f;
            #pragma unroll
            for (int j = 0; j < 8; ++j) {
                bool empty = (uu[j] == SENT);
                float v = funmap(uu[j]);
                f[j] = tobf(empty ? 0.0f : (v - xs[kt][j]));
            }
            Af[2 + kt] = f;
        }

        f32x4 acc[4];
        #pragma unroll
        for (int nt = 0; nt < 4; ++nt) {
            f32x4 a = {bias[nt], bias[nt], bias[nt], bias[nt]};
            acc[nt] = a;
        }
        #pragma unroll
        for (int nt = 0; nt < 4; ++nt)
            #pragma unroll
            for (int kt = 0; kt < 4; ++kt)
                acc[nt] = __builtin_amdgcn_mfma_f32_16x16x32_bf16(Af[kt], Bf[nt][kt], acc[nt], 0, 0, 0);

        #pragma unroll
        for (int nt = 0; nt < 4; ++nt)
            #pragma unroll
            for (int reg = 0; reg < 4; ++reg) {
                int nrow = nodeBase + g * 4 + reg;
                if (nrow < N)
                    out[(size_t)nrow * 64 + nt * 16 + r] = fmaxf(acc[nt][reg], 0.0f);
            }
    }
}

extern "C" void kernel_launch(void* const* d_in, const int* in_sizes, int n_in,
                              void* d_out, int out_size, void* d_ws, size_t ws_size,
                              hipStream_t stream) {
    const float* x  = (const float*)d_in[0];
    const int*   ei = (const int*)d_in[1];
    const float* W  = (const float*)d_in[2];
    const float* b  = (const float*)d_in[3];
    float* out = (float*)d_out;

    int N = in_sizes[0] / 64;
    int E = in_sizes[1] / 2;

    int nsb = (N + NB - 1) >> SB_SHIFT;
    int chunk = (E + NA - 1) / NA;

    size_t counts2_b = (size_t)nsb * NA * 4;
    size_t sbtot_b   = (size_t)((nsb + 63) & ~63) * 4;
    size_t sbbase_b  = (size_t)(nsb + 1 + 63) / 64 * 64 * 4;
    size_t ssrc_b    = (size_t)E * 4;
    size_t need      = counts2_b + sbtot_b + sbbase_b + ssrc_b;

    bool sortPath = (ws_size >= need) && (nsb <= 1024);   // nsb<=1024 -> N<=131072, src fits 17 bits
    if (sortPath) {
        char* p = (char*)d_ws;
        unsigned* counts2 = (unsigned*)p; p += counts2_b;
        unsigned* sbtot   = (unsigned*)p; p += sbtot_b;
        unsigned* sbbase  = (unsigned*)p; p += sbbase_b;
        unsigned* ssrc    = (unsigned*)p;

        histA_kernel<<<NA, 256, 0, stream>>>(ei, counts2, E, nsb, chunk);
        rowscan_kernel<<<(nsb + 7) / 8, 512, 0, stream>>>(counts2, sbtot, nsb);
        sbscan_kernel<<<1, 1024, 0, stream>>>(sbtot, sbbase, nsb);
        placeB_kernel<<<NA, 256, 0, stream>>>(ei, counts2, sbbase, ssrc, E, nsb, chunk);
        fusedB_kernel<<<nsb, 512, 0, stream>>>(x, sbbase, ssrc, W, b, out, N);
    } else {
        size_t need2 = (size_t)N * 64 * 4;
        unsigned int* scratch = (ws_size >= need2) ? (unsigned int*)d_ws : (unsigned int*)d_out;
        init_kernel<<<2048, 256, 0, stream>>>((uint4*)scratch, N * 16);
        long long sthreads = (long long)E * 64;
        int sblocks = (int)((sthreads + 255) / 256);
        scatter_kernel<<<sblocks, 256, 0, stream>>>(x, ei, scratch, E);
        mlp_kernel<<<782, 256, 0, stream>>>(x, scratch, W, b, out, N);
    }
}

// Round 7
// 101.412 us; speedup vs baseline: 2.5371x; 1.5613x over previous
//
#include <hip/hip_runtime.h>
#include <math.h>

#define SENT 0x007FFFFFu         // fmap(-inf)
#define NEGINF_BITS 0xFF800000u  // raw float -inf
#define NA 128                   // hist/place chunk blocks
#define SB_SHIFT 6               // 64 nodes per bucket == reduce block
#define SB_MASK ((1u << SB_SHIFT) - 1u)
#define NB 64                    // nodes per reduce block
#define PITCH 68                 // LDS row pitch (words)
#define MAXSB 2048

typedef __attribute__((ext_vector_type(8))) short bf16x8;
typedef __attribute__((ext_vector_type(4))) float f32x4;

__device__ __forceinline__ unsigned int fmap(float f) {
    unsigned int u = __float_as_uint(f);
    return (u & 0x80000000u) ? ~u : (u | 0x80000000u);
}
__device__ __forceinline__ float funmap(unsigned int u) {
    unsigned int bits = (u & 0x80000000u) ? (u ^ 0x80000000u) : ~u;
    return __uint_as_float(bits);
}
__device__ __forceinline__ short tobf(float f) {
    unsigned int u = __float_as_uint(f);
    u += 0x7FFFu + ((u >> 16) & 1u);
    return (short)(u >> 16);
}

// ---------- counting sort by 64-node bucket (no global atomics) ----------

__global__ void __launch_bounds__(256) histA_kernel(const int* __restrict__ ei,
                                                    unsigned* __restrict__ counts2,
                                                    int E, int nsb, int chunk) {
    __shared__ unsigned h[MAXSB];
    for (int t = threadIdx.x; t < nsb; t += 256) h[t] = 0u;
    __syncthreads();
    int beg = blockIdx.x * chunk;
    int end = min(beg + chunk, E);
    for (int i = beg + threadIdx.x; i < end; i += 256)
        atomicAdd(&h[((unsigned)ei[E + i]) >> SB_SHIFT], 1u);
    __syncthreads();
    for (int t = threadIdx.x; t < nsb; t += 256)
        counts2[(size_t)t * NA + blockIdx.x] = h[t];
}

// one wave per sb: in-place exclusive scan of counts2[sb][0..NA-1]; row total -> sbtot
__global__ void __launch_bounds__(512) rowscan_kernel(unsigned* __restrict__ counts2,
                                                      unsigned* __restrict__ sbtot, int nsb) {
    int lane = threadIdx.x & 63;
    int sb = blockIdx.x * 8 + (threadIdx.x >> 6);
    if (sb >= nsb) return;
    unsigned* row = counts2 + (size_t)sb * NA;
    unsigned a = row[lane];
    unsigned c = row[64 + lane];
    unsigned local = a + c;
    unsigned incl = local;
    #pragma unroll
    for (int d = 1; d < 64; d <<= 1) {
        unsigned t = __shfl_up(incl, d);
        if (lane >= d) incl += t;
    }
    unsigned excl = incl - local;
    row[lane] = excl;
    row[64 + lane] = excl + a;
    if (lane == 63) sbtot[sb] = incl;
}

// chunked single-block exclusive scan of sbtot -> sbbase[0..nsb]
__global__ void __launch_bounds__(1024) sbscan_kernel(const unsigned* __restrict__ sbtot,
                                                      unsigned* __restrict__ sbbase, int nsb) {
    __shared__ unsigned s[1024];
    __shared__ unsigned carry_s;
    if (threadIdx.x == 0) carry_s = 0u;
    __syncthreads();
    for (int chunk = 0; chunk < nsb; chunk += 1024) {
        int i = chunk + threadIdx.x;
        unsigned v = (i < nsb) ? sbtot[i] : 0u;
        s[threadIdx.x] = v;
        __syncthreads();
        for (int d = 1; d < 1024; d <<= 1) {
            unsigned t = (threadIdx.x >= d) ? s[threadIdx.x - d] : 0u;
            __syncthreads();
            s[threadIdx.x] += t;
            __syncthreads();
        }
        unsigned carry = carry_s;
        if (i < nsb) sbbase[i] = carry + s[threadIdx.x] - v;
        __syncthreads();
        if (threadIdx.x == 1023) carry_s = carry + s[1023];
        __syncthreads();
    }
    if (threadIdx.x == 0) sbbase[nsb] = carry_s;
}

// placement: LDS cursors preloaded with sbbase+rowbase; exclusive (sb,blk) regions
__global__ void __launch_bounds__(256) placeB_kernel(const int* __restrict__ ei,
                                                     const unsigned* __restrict__ counts2,
                                                     const unsigned* __restrict__ sbbase,
                                                     unsigned* __restrict__ ssrc,
                                                     int E, int nsb, int chunk) {
    __shared__ unsigned fill[MAXSB];
    for (int t = threadIdx.x; t < nsb; t += 256)
        fill[t] = sbbase[t] + counts2[(size_t)t * NA + blockIdx.x];
    __syncthreads();
    int beg = blockIdx.x * chunk;
    int end = min(beg + chunk, E);
    for (int i = beg + threadIdx.x; i < end; i += 256) {
        unsigned src = (unsigned)ei[i];
        unsigned dst = (unsigned)ei[E + i];
        unsigned pos = atomicAdd(&fill[dst >> SB_SHIFT], 1u);
        ssrc[pos] = (src << SB_SHIFT) | (dst & SB_MASK);
    }
}

// ---------- segment-max reduce (bucket == block), 16-deep gather batches ----------
__global__ void __launch_bounds__(256, 6) reduceB_kernel(const float* __restrict__ x,
                                                         const unsigned* __restrict__ sbbase,
                                                         const unsigned* __restrict__ ssrc,
                                                         float* __restrict__ xj, int N) {
    __shared__ unsigned M[NB * PITCH];   // 17.4 KiB
    int tid = threadIdx.x;
    int lane = tid & 63;
    int wid = tid >> 6;                  // 4 waves

    for (int i = tid; i < NB * PITCH; i += 256) M[i] = SENT;

    int nodeBase = blockIdx.x * NB;
    int beg = (int)sbbase[blockIdx.x];
    int end = (int)sbbase[blockIdx.x + 1];
    __syncthreads();

    for (int i0 = beg + wid * 64; i0 < end; i0 += 256) {
        int i = i0 + lane;
        unsigned p = (i < end) ? ssrc[i] : 0u;
        int cnt = min(64, end - i0);
        unsigned pfirst = __shfl(p, 0);
        for (int j = 0; j < cnt; j += 16) {
            unsigned pp[16];
            float vv[16];
            #pragma unroll
            for (int k = 0; k < 16; ++k) {
                pp[k] = (j + k < cnt) ? __shfl(p, j + k) : pfirst;  // dup idempotent
                vv[k] = x[(size_t)(pp[k] >> SB_SHIFT) * 64 + lane];
            }
            #pragma unroll
            for (int k = 0; k < 16; ++k)
                atomicMax(&M[(pp[k] & SB_MASK) * PITCH + lane], fmap(vv[k]));
        }
    }
    __syncthreads();

    // dump raw float max (-inf sentinel survives); subtraction folded into MLP
    for (int row = wid; row < NB; row += 4) {
        int n = nodeBase + row;
        if (n < N) xj[(size_t)n * 64 + lane] = funmap(M[row * PITCH + lane]);
    }
}

// ---------- MFMA concat-GEMM-ReLU ----------
// MAPPED=true: xj fmap-encoded (atomic fallback); false: raw float with -inf sentinel.
// xj may alias out: each tile's xj reads precede its stores (data dep through acc).
template <bool MAPPED>
__global__ void __launch_bounds__(256) mlp_kernel(const float* __restrict__ x,
                                                  const unsigned int* xj,
                                                  const float* __restrict__ W,
                                                  const float* __restrict__ b,
                                                  float* out, int N) {
    int lane = threadIdx.x & 63;
    int wid  = threadIdx.x >> 6;
    int r = lane & 15;
    int g = lane >> 4;

    bf16x8 Bf[4][4];
    #pragma unroll
    for (int nt = 0; nt < 4; ++nt)
        #pragma unroll
        for (int kt = 0; kt < 4; ++kt) {
            const float* wp = W + (size_t)(kt * 32 + g * 8) * 64 + nt * 16 + r;
            bf16x8 f;
            #pragma unroll
            for (int j = 0; j < 8; ++j) f[j] = tobf(wp[(size_t)j * 64]);
            Bf[nt][kt] = f;
        }
    float bias[4];
    #pragma unroll
    for (int nt = 0; nt < 4; ++nt) bias[nt] = b[nt * 16 + r];

    int nTiles = (N + 15) >> 4;
    int totalWaves = gridDim.x * 4;
    for (int tile = blockIdx.x * 4 + wid; tile < nTiles; tile += totalWaves) {
        int nodeBase = tile << 4;
        int rowIdx = min(nodeBase + r, N - 1);
        const float* xp = x + (size_t)rowIdx * 64;
        const unsigned int* jp = xj + (size_t)rowIdx * 64;

        bf16x8 Af[4];
        float xs[2][8];
        #pragma unroll
        for (int kt = 0; kt < 2; ++kt) {
            float4 flo = *(const float4*)(xp + kt * 32 + g * 8);
            float4 fhi = *(const float4*)(xp + kt * 32 + g * 8 + 4);
            xs[kt][0] = flo.x; xs[kt][1] = flo.y; xs[kt][2] = flo.z; xs[kt][3] = flo.w;
            xs[kt][4] = fhi.x; xs[kt][5] = fhi.y; xs[kt][6] = fhi.z; xs[kt][7] = fhi.w;
            bf16x8 f;
            #pragma unroll
            for (int j = 0; j < 8; ++j) f[j] = tobf(xs[kt][j]);
            Af[kt] = f;
        }
        #pragma unroll
        for (int kt = 0; kt < 2; ++kt) {
            uint4 ulo = *(const uint4*)(jp + kt * 32 + g * 8);
            uint4 uhi = *(const uint4*)(jp + kt * 32 + g * 8 + 4);
            unsigned int uu[8] = {ulo.x, ulo.y, ulo.z, ulo.w, uhi.x, uhi.y, uhi.z, uhi.w};
            bf16x8 f;
            #pragma unroll
            for (int j = 0; j < 8; ++j) {
                bool empty;
                float v;
                if (MAPPED) { empty = (uu[j] == SENT); v = funmap(uu[j]); }
                else        { empty = (uu[j] == NEGINF_BITS); v = __uint_as_float(uu[j]); }
                f[j] = tobf(empty ? 0.0f : (v - xs[kt][j]));
            }
            Af[2 + kt] = f;
        }

        f32x4 acc[4];
        #pragma unroll
        for (int nt = 0; nt < 4; ++nt) {
            f32x4 a = {bias[nt], bias[nt], bias[nt], bias[nt]};
            acc[nt] = a;
        }
        #pragma unroll
        for (int nt = 0; nt < 4; ++nt)
            #pragma unroll
            for (int kt = 0; kt < 4; ++kt)
                acc[nt] = __builtin_amdgcn_mfma_f32_16x16x32_bf16(Af[kt], Bf[nt][kt], acc[nt], 0, 0, 0);

        #pragma unroll
        for (int nt = 0; nt < 4; ++nt)
            #pragma unroll
            for (int reg = 0; reg < 4; ++reg) {
                int nrow = nodeBase + g * 4 + reg;
                if (nrow < N)
                    out[(size_t)nrow * 64 + nt * 16 + r] = fmaxf(acc[nt][reg], 0.0f);
            }
    }
}

// ---------------- atomic fallback path ----------------

__global__ void init_kernel(uint4* __restrict__ ws, int n4) {
    int i = blockIdx.x * blockDim.x + threadIdx.x;
    int stride = gridDim.x * blockDim.x;
    uint4 v = make_uint4(SENT, SENT, SENT, SENT);
    for (; i < n4; i += stride) ws[i] = v;
}

__global__ void scatter_kernel(const float* __restrict__ x,
                               const int* __restrict__ ei,
                               unsigned int* __restrict__ ws, int E) {
    long long gid = (long long)blockIdx.x * blockDim.x + threadIdx.x;
    int e = (int)(gid >> 6);
    int lane = (int)(gid & 63);
    if (e >= E) return;
    int src = ei[e];
    int dst = ei[E + e];
    unsigned int m = fmap(x[(size_t)src * 64 + lane]);
    unsigned int* p = ws + (size_t)dst * 64 + lane;
    if (m > *p) atomicMax(p, m);
}

extern "C" void kernel_launch(void* const* d_in, const int* in_sizes, int n_in,
                              void* d_out, int out_size, void* d_ws, size_t ws_size,
                              hipStream_t stream) {
    const float* x  = (const float*)d_in[0];
    const int*   ei = (const int*)d_in[1];
    const float* W  = (const float*)d_in[2];
    const float* b  = (const float*)d_in[3];
    float* out = (float*)d_out;

    int N = in_sizes[0] / 64;
    int E = in_sizes[1] / 2;

    int nsb = (N + NB - 1) >> SB_SHIFT;
    int chunk = (E + NA - 1) / NA;

    size_t counts2_b = (size_t)nsb * NA * 4;
    size_t sbtot_b   = (size_t)((nsb + 63) & ~63) * 4;
    size_t sbbase_b  = (size_t)(nsb + 1 + 63) / 64 * 64 * 4;
    size_t ssrc_b    = (size_t)E * 4;
    size_t xj_b      = (size_t)N * 64 * 4;
    size_t need      = counts2_b + sbtot_b + sbbase_b + ssrc_b;

    bool sortPath = (ws_size >= need) && (nsb <= MAXSB);
    if (sortPath) {
        char* p = (char*)d_ws;
        unsigned* counts2 = (unsigned*)p; p += counts2_b;
        unsigned* sbtot   = (unsigned*)p; p += sbtot_b;
        unsigned* sbbase  = (unsigned*)p; p += sbbase_b;
        unsigned* ssrc    = (unsigned*)p; p += ssrc_b;
        float* xjp = (ws_size >= need + xj_b) ? (float*)p : (float*)d_out;

        histA_kernel<<<NA, 256, 0, stream>>>(ei, counts2, E, nsb, chunk);
        rowscan_kernel<<<(nsb + 7) / 8, 512, 0, stream>>>(counts2, sbtot, nsb);
        sbscan_kernel<<<1, 1024, 0, stream>>>(sbtot, sbbase, nsb);
        placeB_kernel<<<NA, 256, 0, stream>>>(ei, counts2, sbbase, ssrc, E, nsb, chunk);
        reduceB_kernel<<<nsb, 256, 0, stream>>>(x, sbbase, ssrc, xjp, N);
        mlp_kernel<false><<<782, 256, 0, stream>>>(x, (const unsigned*)xjp, W, b, out, N);
    } else {
        size_t need2 = (size_t)N * 64 * 4;
        unsigned int* scratch = (ws_size >= need2) ? (unsigned int*)d_ws : (unsigned int*)d_out;
        init_kernel<<<2048, 256, 0, stream>>>((uint4*)scratch, N * 16);
        long long sthreads = (long long)E * 64;
        int sblocks = (int)((sthreads + 255) / 256);
        scatter_kernel<<<sblocks, 256, 0, stream>>>(x, ei, scratch, E);
        mlp_kernel<true><<<782, 256, 0, stream>>>(x, scratch, W, b, out, N);
    }
}